// Round 1
// baseline (772.881 us; speedup 1.0000x reference)
//
#include <hip/hip_runtime.h>
#include <math.h>

#define NROWS 65536
#define DDIM  64
#define KCODE 4096
#define TK    128
#define NSPLIT 4
#define KSPL  (KCODE / NSPLIT)

// output layout (float offsets), concatenated in reference return order
#define O_Q    0           // quantized_st [B,T,D] = 4194304
#define O_LOSS 4194304     // loss scalar
#define O_IDX  4194305     // encoding_indices [B,T] = 65536 (written as floats)
#define O_NW   4259841     // new_weight [K,D] = 262144
#define O_CS   4521985     // cs [K] = 4096
#define O_NEW  4526081     // new_ema_w [K,D] = 262144

// ---------------- Kernel A: init + ||e||^2 precompute ----------------
// O5 := DECAY*ema_w (dw accumulates into it later), O4 := 0 (counts),
// B2_k := f32 sum of w[k,:]^2 stashed in O3[0..K) (O3 fully rewritten at the end).
__global__ __launch_bounds__(256)
void vq_prep(const float* __restrict__ w, const float* __restrict__ ema_w,
             float* __restrict__ out, double* __restrict__ loss_acc) {
    int i = blockIdx.x * 256 + threadIdx.x;   // grid covers K*D = 262144
    if (i < KCODE * DDIM) out[O_NEW + i] = 0.99f * ema_w[i];
    if (i < KCODE) {
        out[O_CS + i] = 0.0f;
        const float4* wr = (const float4*)(w + (size_t)i * DDIM);
        float ax = 0.f, ay = 0.f, az = 0.f, aw = 0.f;
        #pragma unroll
        for (int j = 0; j < 16; ++j) {
            float4 v = wr[j];
            ax += v.x * v.x; ay += v.y * v.y; az += v.z * v.z; aw += v.w * v.w;
        }
        out[O_NW + i] = (ax + ay) + (az + aw);
    }
    if (i == 0) *loss_acc = 0.0;
}

// ---------------- Kernel B1: split-K fused score + argmin ----------------
// block = 256 threads (1 row each), blockIdx.y = K-split. Codes staged in LDS
// 128 at a time; all 64 lanes read the same code element (LDS broadcast).
// Score replicates the reference's f32 rounding: fl(fl(A + B_k) - 2*dot).
__global__ __launch_bounds__(256, 4)
void vq_argmin(const float* __restrict__ x, const float* __restrict__ w,
               const float* __restrict__ b2, float* __restrict__ spart,
               float* __restrict__ ipart) {
    __shared__ __align__(16) float lds[TK * DDIM];
    __shared__ float bsh[TK];
    const int tid = threadIdx.x;
    const int row = blockIdx.x * 256 + tid;
    const int k0  = blockIdx.y * KSPL;

    float4 xr[16];
    const float4* xp = (const float4*)(x + (size_t)row * DDIM);
    float ax = 0.f, ay = 0.f, az = 0.f, aw = 0.f;
    #pragma unroll
    for (int j = 0; j < 16; ++j) {
        xr[j] = xp[j];
        ax += xr[j].x * xr[j].x; ay += xr[j].y * xr[j].y;
        az += xr[j].z * xr[j].z; aw += xr[j].w * xr[j].w;
    }
    const float A = (ax + ay) + (az + aw);   // grid-shift invariant: order is free

    float best = INFINITY;
    int bidx = 0;

    for (int t = 0; t < KSPL; t += TK) {
        __syncthreads();
        const float4* wsrc = (const float4*)(w + (size_t)(k0 + t) * DDIM);
        float4* ldst = (float4*)lds;
        #pragma unroll
        for (int j = 0; j < 8; ++j)              // 8*256 = 2048 float4 = TK*DDIM
            ldst[tid + j * 256] = wsrc[tid + j * 256];
        if (tid < TK) bsh[tid] = b2[k0 + t + tid];
        __syncthreads();
        #pragma unroll 2
        for (int kk = 0; kk < TK; ++kk) {
            const float4* e4 = (const float4*)(lds + kk * DDIM);
            float cx = 0.f, cy = 0.f, cz = 0.f, cw = 0.f;
            #pragma unroll
            for (int j = 0; j < 16; ++j) {
                float4 e = e4[j];
                cx += e.x * xr[j].x; cy += e.y * xr[j].y;
                cz += e.z * xr[j].z; cw += e.w * xr[j].w;
            }
            float dot = (cx + cy) + (cz + cw);
            // 2*dot is exact (power of 2); (A+B) then subtract matches jnp order
            float s = (A + bsh[kk]) - 2.0f * dot;
            if (s < best) { best = s; bidx = k0 + t + kk; }   // strict <: lowest idx on tie
        }
    }
    spart[(size_t)row * NSPLIT + blockIdx.y] = best;
    ipart[(size_t)row * NSPLIT + blockIdx.y] = (float)bidx;
}

// ---------------- Kernel B2: merge split partials -> indices ----------------
__global__ __launch_bounds__(256)
void vq_merge(const float* __restrict__ spart, const float* __restrict__ ipart,
              float* __restrict__ oidx) {
    int n = blockIdx.x * 256 + threadIdx.x;
    float best = INFINITY, bi = 0.f;
    #pragma unroll
    for (int s = 0; s < NSPLIT; ++s) {          // ascending splits = ascending idx ranges
        float v = spart[(size_t)n * NSPLIT + s];
        float id = ipart[(size_t)n * NSPLIT + s];
        if (v < best) { best = v; bi = id; }    // strict <: lowest idx on tie
    }
    oidx[n] = bi;
}

// ---------------- Kernel C: gather + ST output + dw/count atomics + loss ----------------
// 16 lanes per row (float4 each), 16 rows per 256-thread block.
__global__ __launch_bounds__(256)
void vq_gather(const float* __restrict__ x, const float* __restrict__ w,
               float* __restrict__ out, double* __restrict__ loss_acc) {
    const int tid = threadIdx.x;
    const int l16 = tid & 15;
    const int row = blockIdx.x * 16 + (tid >> 4);
    const int k = (int)out[O_IDX + row];
    const float4 w4 = ((const float4*)(w + (size_t)k * DDIM))[l16];
    const float4 x4 = ((const float4*)(x + (size_t)row * DDIM))[l16];
    // straight-through: replicate fl(x + fl(q - x)) exactly
    float4 o;
    o.x = x4.x + (w4.x - x4.x);
    o.y = x4.y + (w4.y - x4.y);
    o.z = x4.z + (w4.z - x4.z);
    o.w = x4.w + (w4.w - x4.w);
    ((float4*)(out + O_Q + (size_t)row * DDIM))[l16] = o;
    // dw: accumulate 0.01*x into new_ema_w (pre-initialized to 0.99*ema_w)
    float* dwp = out + O_NEW + (size_t)k * DDIM + l16 * 4;
    atomicAdd(dwp + 0, 0.01f * x4.x);
    atomicAdd(dwp + 1, 0.01f * x4.y);
    atomicAdd(dwp + 2, 0.01f * x4.z);
    atomicAdd(dwp + 3, 0.01f * x4.w);
    if (l16 == 0) atomicAdd(out + O_CS + k, 1.0f);   // exact integer counts in f32
    // loss partial: (q - x)^2
    float dx = w4.x - x4.x, dy = w4.y - x4.y, dz = w4.z - x4.z, dw_ = w4.w - x4.w;
    float e = dx * dx + dy * dy + dz * dz + dw_ * dw_;
    #pragma unroll
    for (int off = 32; off > 0; off >>= 1) e += __shfl_down(e, off);
    if ((tid & 63) == 0) atomicAdd(loss_acc, (double)e);
}

// ---------------- Kernel D: Laplace-smoothed cluster sizes + loss write ----------------
__global__ __launch_bounds__(1024)
void vq_cs(const float* __restrict__ ecs, float* __restrict__ out,
           const double* __restrict__ loss_acc) {
    __shared__ float red[1024];
    const int tid = threadIdx.x;
    float cs[4];
    float local = 0.f;
    #pragma unroll
    for (int j = 0; j < 4; ++j) {
        int k = j * 1024 + tid;
        float cnt = out[O_CS + k];
        cs[j] = ecs[k] * 0.99f + 0.01f * cnt;
        local += cs[j];
    }
    red[tid] = local;
    for (int s = 512; s > 0; s >>= 1) {
        __syncthreads();
        if (tid < s) red[tid] += red[tid + s];
    }
    __syncthreads();
    const float n = red[0];
    const float denom = n + 0.04096f;     // n + K*EPS
    #pragma unroll
    for (int j = 0; j < 4; ++j) {
        int k = j * 1024 + tid;
        out[O_CS + k] = (cs[j] + 1e-5f) / denom * n;
    }
    if (tid == 0) out[O_LOSS] = 1.25f * (float)(*loss_acc / 4194304.0);
}

// ---------------- Kernel E: new_weight = new_ema_w / cs ----------------
__global__ __launch_bounds__(256)
void vq_final(float* __restrict__ out) {
    int i = blockIdx.x * 256 + threadIdx.x;
    if (i >= KCODE * DDIM) return;
    int k = i >> 6;
    out[O_NW + i] = out[O_NEW + i] / out[O_CS + k];
}

extern "C" void kernel_launch(void* const* d_in, const int* in_sizes, int n_in,
                              void* d_out, int out_size, void* d_ws, size_t ws_size,
                              hipStream_t stream) {
    (void)in_sizes; (void)n_in; (void)out_size; (void)ws_size;
    const float* x    = (const float*)d_in[0];
    const float* w    = (const float*)d_in[1];
    const float* ecs  = (const float*)d_in[2];
    const float* emaw = (const float*)d_in[3];
    float* out = (float*)d_out;
    double* lacc = (double*)d_ws;   // 8 bytes of ws for the loss accumulator

    // partials live in the O_Q region (rewritten each call, overwritten by vq_gather)
    float* spart = out;                     // [NROWS*NSPLIT]
    float* ipart = out + NROWS * NSPLIT;    // [NROWS*NSPLIT]

    vq_prep  <<<1024, 256, 0, stream>>>(w, emaw, out, lacc);
    vq_argmin<<<dim3(256, NSPLIT), 256, 0, stream>>>(x, w, out + O_NW, spart, ipart);
    vq_merge <<<256, 256, 0, stream>>>(spart, ipart, out + O_IDX);
    vq_gather<<<4096, 256, 0, stream>>>(x, w, out, lacc);
    vq_cs    <<<1, 1024, 0, stream>>>(ecs, out, lacc);
    vq_final <<<1024, 256, 0, stream>>>(out);
}

// Round 2
// 691.757 us; speedup vs baseline: 1.1173x; 1.1173x over previous
//
#include <hip/hip_runtime.h>
#include <math.h>

#define NROWS 65536
#define DDIM  64
#define KCODE 4096

// output layout (float offsets), concatenated in reference return order
#define O_Q    0           // quantized_st [B,T,D] = 4194304
#define O_LOSS 4194304     // loss scalar
#define O_IDX  4194305     // encoding_indices [B,T] = 65536 (floats)
#define O_NW   4259841     // new_weight [K,D] = 262144
#define O_CS   4521985     // cs [K] = 4096
#define O_NEW  4526081     // new_ema_w [K,D] = 262144

// scratch inside O_Q (overwritten later by vq_gather):
//   E_hi : halves [0, 262144)        = floats [0, 131072)
//   E_lo : halves [262144, 524288)   = floats [131072, 262144)
//   A    : floats [262144, 327680)
#define O_A    262144

typedef _Float16 f16x8 __attribute__((ext_vector_type(8)));
typedef float    f32x4 __attribute__((ext_vector_type(4)));

// ---------------- Kernel A: init + splits + norms ----------------
__global__ __launch_bounds__(256)
void vq_prep(const float* __restrict__ x, const float* __restrict__ w,
             const float* __restrict__ ema_w, float* __restrict__ out,
             double* __restrict__ loss_acc) {
    int i = blockIdx.x * 256 + threadIdx.x;   // grid = 262144 threads
    if (i < KCODE * DDIM) {
        out[O_NEW + i] = 0.99f * ema_w[i];
        // scaled f16 split of codes: E = w*2^12; E_lo = f16((E - E_hi)*2^12)
        float E = w[i] * 4096.0f;
        _Float16 h = (_Float16)E;
        float r = E - (float)h;
        _Float16 lo = (_Float16)(r * 4096.0f);
        ((_Float16*)out)[i] = h;
        ((_Float16*)out)[262144 + i] = lo;
    }
    if (i < NROWS) {  // A[row] = ||x_row||^2, EXACT same order as round-1 kernel
        const float4* xr = (const float4*)(x + (size_t)i * DDIM);
        float ax = 0.f, ay = 0.f, az = 0.f, aw = 0.f;
        #pragma unroll
        for (int j = 0; j < 16; ++j) {
            float4 v = xr[j];
            ax += v.x * v.x; ay += v.y * v.y; az += v.z * v.z; aw += v.w * v.w;
        }
        out[O_A + i] = (ax + ay) + (az + aw);
    }
    if (i < KCODE) {  // B2[k] = ||e_k||^2, same order as before
        out[O_CS + i] = 0.0f;
        const float4* wr = (const float4*)(w + (size_t)i * DDIM);
        float ax = 0.f, ay = 0.f, az = 0.f, aw = 0.f;
        #pragma unroll
        for (int j = 0; j < 16; ++j) {
            float4 v = wr[j];
            ax += v.x * v.x; ay += v.y * v.y; az += v.z * v.z; aw += v.w * v.w;
        }
        out[O_NW + i] = (ax + ay) + (az + aw);
    }
    if (i == 0) *loss_acc = 0.0;
}

__device__ inline void split8(float4 a, float4 b, f16x8& hi, f16x8& lo) {
    float v0 = a.x, v1 = a.y, v2 = a.z, v3 = a.w;
    float v4 = b.x, v5 = b.y, v6 = b.z, v7 = b.w;
    float vv[8] = {v0, v1, v2, v3, v4, v5, v6, v7};
    #pragma unroll
    for (int j = 0; j < 8; ++j) {
        float X = vv[j] * 256.0f;           // x*2^8
        _Float16 h = (_Float16)X;
        float r = X - (float)h;             // exact (Sterbenz)
        hi[j] = h;
        lo[j] = (_Float16)(r * 4096.0f);    // residual*2^12
    }
}

// ---------------- Kernel B: MFMA fused score + argmin ----------------
// 1024 blocks x 256 thr (4 waves). Wave w owns rows blk*64 + w*16; scans all
// 4096 codes in 256 steps of 16 (one 16x16x32 f16 MFMA tile, 3 split passes).
__global__ __launch_bounds__(256)
void vq_argmin_mfma(const float* __restrict__ x,
                    const _Float16* __restrict__ ehi,
                    const _Float16* __restrict__ elo,
                    const float* __restrict__ Ag,
                    const float* __restrict__ b2g,
                    float* __restrict__ oidx) {
    __shared__ __align__(16) float b2sh[KCODE];
    const int tid = threadIdx.x;
    #pragma unroll
    for (int j = 0; j < 4; ++j)
        ((float4*)b2sh)[tid + j * 256] = ((const float4*)b2g)[tid + j * 256];
    __syncthreads();

    const int l   = tid & 63;
    const int w   = tid >> 6;
    const int g   = l >> 4;        // k-group (0..3)
    const int c16 = l & 15;        // A: row within tile / B: code within tile
    const int rowbase = blockIdx.x * 64 + w * 16;

    // A-operand fragments: rows rowbase+c16, k = g*8 + {0..7} + 32*ks
    f16x8 xh0, xh1, xl0, xl1;
    {
        const float* xr = x + (size_t)(rowbase + c16) * DDIM + g * 8;
        float4 a0 = *(const float4*)(xr);
        float4 a1 = *(const float4*)(xr + 4);
        float4 a2 = *(const float4*)(xr + 32);
        float4 a3 = *(const float4*)(xr + 36);
        split8(a0, a1, xh0, xl0);
        split8(a2, a3, xh1, xl1);
    }
    // per-lane epilogue rows: 4*g + v  (C/D layout: col=lane&15, row=(lane>>4)*4+v)
    float A_reg[4];
    #pragma unroll
    for (int v = 0; v < 4; ++v) A_reg[v] = Ag[rowbase + 4 * g + v];

    float bestv[4]; int bidx[4];
    #pragma unroll
    for (int v = 0; v < 4; ++v) { bestv[v] = INFINITY; bidx[v] = 0; }

    const _Float16* pbh = ehi + (size_t)c16 * DDIM + g * 8;
    const _Float16* pbl = elo + (size_t)c16 * DDIM + g * 8;

    f16x8 bh0 = *(const f16x8*)(pbh);
    f16x8 bh1 = *(const f16x8*)(pbh + 32);
    f16x8 bl0 = *(const f16x8*)(pbl);
    f16x8 bl1 = *(const f16x8*)(pbl + 32);
    float b2c = b2sh[c16];

    #pragma unroll 2
    for (int s = 0; s < 256; ++s) {
        const int sn = (s + 1) & 255;                 // wrap: dead load at s=255
        const size_t so = (size_t)sn * 1024;          // 16 codes * 64 halves
        f16x8 nh0 = *(const f16x8*)(pbh + so);
        f16x8 nh1 = *(const f16x8*)(pbh + so + 32);
        f16x8 nl0 = *(const f16x8*)(pbl + so);
        f16x8 nl1 = *(const f16x8*)(pbl + so + 32);
        float nb2 = b2sh[sn * 16 + c16];

        f32x4 acc1 = {0.f, 0.f, 0.f, 0.f};
        f32x4 acc2 = {0.f, 0.f, 0.f, 0.f};
        acc1 = __builtin_amdgcn_mfma_f32_16x16x32_f16(xh0, bh0, acc1, 0, 0, 0);
        acc1 = __builtin_amdgcn_mfma_f32_16x16x32_f16(xh1, bh1, acc1, 0, 0, 0);
        acc2 = __builtin_amdgcn_mfma_f32_16x16x32_f16(xl0, bh0, acc2, 0, 0, 0);
        acc2 = __builtin_amdgcn_mfma_f32_16x16x32_f16(xl1, bh1, acc2, 0, 0, 0);
        acc2 = __builtin_amdgcn_mfma_f32_16x16x32_f16(xh0, bl0, acc2, 0, 0, 0);
        acc2 = __builtin_amdgcn_mfma_f32_16x16x32_f16(xh1, bl1, acc2, 0, 0, 0);

        const int c = s * 16 + c16;
        #pragma unroll
        for (int v = 0; v < 4; ++v) {
            // dot*2^20 = acc1 + 2^-12*acc2 (one rounding, fma)
            float dotc = fmaf(acc2[v], 0x1p-12f, acc1[v]);
            float t = A_reg[v] + b2c;                  // fl(A + B_k)
            float sc = fmaf(dotc, -0x1p-19f, t);       // fl(t - 2*dot), mul exact
            if (sc < bestv[v]) { bestv[v] = sc; bidx[v] = c; }  // strict <
        }
        bh0 = nh0; bh1 = nh1; bl0 = nl0; bl1 = nl1; b2c = nb2;
    }

    // reduce (value, then lowest index) across the 16 lanes of each k-group
    #pragma unroll
    for (int off = 1; off < 16; off <<= 1) {
        #pragma unroll
        for (int v = 0; v < 4; ++v) {
            float ob = __shfl_xor(bestv[v], off);
            int   oi = __shfl_xor(bidx[v], off);
            if (ob < bestv[v] || (ob == bestv[v] && oi < bidx[v])) {
                bestv[v] = ob; bidx[v] = oi;
            }
        }
    }
    if (c16 == 0) {
        #pragma unroll
        for (int v = 0; v < 4; ++v)
            oidx[rowbase + 4 * g + v] = (float)bidx[v];
    }
}

// ---------------- Kernel C: gather + ST output + dw/count atomics + loss ----------------
__global__ __launch_bounds__(256)
void vq_gather(const float* __restrict__ x, const float* __restrict__ w,
               float* __restrict__ out, double* __restrict__ loss_acc) {
    const int tid = threadIdx.x;
    const int l16 = tid & 15;
    const int row = blockIdx.x * 16 + (tid >> 4);
    const int k = (int)out[O_IDX + row];
    const float4 w4 = ((const float4*)(w + (size_t)k * DDIM))[l16];
    const float4 x4 = ((const float4*)(x + (size_t)row * DDIM))[l16];
    float4 o;
    o.x = x4.x + (w4.x - x4.x);
    o.y = x4.y + (w4.y - x4.y);
    o.z = x4.z + (w4.z - x4.z);
    o.w = x4.w + (w4.w - x4.w);
    ((float4*)(out + O_Q + (size_t)row * DDIM))[l16] = o;
    float* dwp = out + O_NEW + (size_t)k * DDIM + l16 * 4;
    atomicAdd(dwp + 0, 0.01f * x4.x);
    atomicAdd(dwp + 1, 0.01f * x4.y);
    atomicAdd(dwp + 2, 0.01f * x4.z);
    atomicAdd(dwp + 3, 0.01f * x4.w);
    if (l16 == 0) atomicAdd(out + O_CS + k, 1.0f);
    float dx = w4.x - x4.x, dy = w4.y - x4.y, dz = w4.z - x4.z, dw_ = w4.w - x4.w;
    float e = dx * dx + dy * dy + dz * dz + dw_ * dw_;
    #pragma unroll
    for (int off = 32; off > 0; off >>= 1) e += __shfl_down(e, off);
    if ((tid & 63) == 0) atomicAdd(loss_acc, (double)e);
}

// ---------------- Kernel D: Laplace smoothing + loss write ----------------
__global__ __launch_bounds__(1024)
void vq_cs(const float* __restrict__ ecs, float* __restrict__ out,
           const double* __restrict__ loss_acc) {
    __shared__ float red[1024];
    const int tid = threadIdx.x;
    float cs[4];
    float local = 0.f;
    #pragma unroll
    for (int j = 0; j < 4; ++j) {
        int k = j * 1024 + tid;
        float cnt = out[O_CS + k];
        cs[j] = ecs[k] * 0.99f + 0.01f * cnt;
        local += cs[j];
    }
    red[tid] = local;
    for (int s = 512; s > 0; s >>= 1) {
        __syncthreads();
        if (tid < s) red[tid] += red[tid + s];
    }
    __syncthreads();
    const float n = red[0];
    const float denom = n + 0.04096f;
    #pragma unroll
    for (int j = 0; j < 4; ++j) {
        int k = j * 1024 + tid;
        out[O_CS + k] = (cs[j] + 1e-5f) / denom * n;
    }
    if (tid == 0) out[O_LOSS] = 1.25f * (float)(*loss_acc / 4194304.0);
}

// ---------------- Kernel E: new_weight = new_ema_w / cs ----------------
__global__ __launch_bounds__(256)
void vq_final(float* __restrict__ out) {
    int i = blockIdx.x * 256 + threadIdx.x;
    if (i >= KCODE * DDIM) return;
    int k = i >> 6;
    out[O_NW + i] = out[O_NEW + i] / out[O_CS + k];
}

extern "C" void kernel_launch(void* const* d_in, const int* in_sizes, int n_in,
                              void* d_out, int out_size, void* d_ws, size_t ws_size,
                              hipStream_t stream) {
    (void)in_sizes; (void)n_in; (void)out_size; (void)ws_size;
    const float* x    = (const float*)d_in[0];
    const float* w    = (const float*)d_in[1];
    const float* ecs  = (const float*)d_in[2];
    const float* emaw = (const float*)d_in[3];
    float* out = (float*)d_out;
    double* lacc = (double*)d_ws;

    const _Float16* ehi = (const _Float16*)out;            // halves [0, 262144)
    const _Float16* elo = ((const _Float16*)out) + 262144; // halves [262144, 524288)
    const float*    Ag  = out + O_A;

    vq_prep       <<<1024, 256, 0, stream>>>(x, w, emaw, out, lacc);
    vq_argmin_mfma<<<1024, 256, 0, stream>>>(x, ehi, elo, Ag, out + O_NW, out + O_IDX);
    vq_gather     <<<4096, 256, 0, stream>>>(x, w, out, lacc);
    vq_cs         <<<1, 1024, 0, stream>>>(ecs, out, lacc);
    vq_final      <<<1024, 256, 0, stream>>>(out);
}

// Round 3
// 473.887 us; speedup vs baseline: 1.6309x; 1.4597x over previous
//
#include <hip/hip_runtime.h>
#include <math.h>

#define NROWS 65536
#define DDIM  64
#define KCODE 4096
#define NSPLIT 2
#define KSPL  (KCODE / NSPLIT)
#define STEPS (KSPL / 16)          // 128

// output layout (float offsets), concatenated in reference return order
#define O_Q    0           // quantized_st [B,T,D] = 4194304
#define O_LOSS 4194304     // loss scalar
#define O_IDX  4194305     // encoding_indices [B,T] = 65536 (floats)
#define O_NW   4259841     // new_weight [K,D] = 262144
#define O_CS   4521985     // cs [K] = 4096
#define O_NEW  4526081     // new_ema_w [K,D] = 262144

// scratch inside O_Q (overwritten later by vq_gather):
//   E_hi : halves [0, 262144)        = floats [0, 131072)
//   E_lo : halves [262144, 524288)   = floats [131072, 262144)
//   A    : floats [262144, 327680)
//   spart: floats [327680, 458752)   (row*NSPLIT + split)
//   ipart: floats [458752, 589824)
#define O_A    262144
#define O_SP   327680
#define O_IP   458752

typedef _Float16 f16x8 __attribute__((ext_vector_type(8)));
typedef float    f32x4 __attribute__((ext_vector_type(4)));

// ---------------- Kernel A: init + splits + norms ----------------
__global__ __launch_bounds__(256)
void vq_prep(const float* __restrict__ x, const float* __restrict__ w,
             const float* __restrict__ ema_w, float* __restrict__ out,
             double* __restrict__ loss_acc) {
    int i = blockIdx.x * 256 + threadIdx.x;   // grid = 262144 threads
    if (i < KCODE * DDIM) {
        out[O_NEW + i] = 0.99f * ema_w[i];
        // scaled f16 split of codes: E = w*2^12; E_lo = f16((E - E_hi)*2^12)
        float E = w[i] * 4096.0f;
        _Float16 h = (_Float16)E;
        float r = E - (float)h;
        _Float16 lo = (_Float16)(r * 4096.0f);
        ((_Float16*)out)[i] = h;
        ((_Float16*)out)[262144 + i] = lo;
    }
    if (i < NROWS) {  // A[row] = ||x_row||^2 (same order as validated rounds)
        const float4* xr = (const float4*)(x + (size_t)i * DDIM);
        float ax = 0.f, ay = 0.f, az = 0.f, aw = 0.f;
        #pragma unroll
        for (int j = 0; j < 16; ++j) {
            float4 v = xr[j];
            ax += v.x * v.x; ay += v.y * v.y; az += v.z * v.z; aw += v.w * v.w;
        }
        out[O_A + i] = (ax + ay) + (az + aw);
    }
    if (i < KCODE) {  // B2[k] = ||e_k||^2
        out[O_CS + i] = 0.0f;
        const float4* wr = (const float4*)(w + (size_t)i * DDIM);
        float ax = 0.f, ay = 0.f, az = 0.f, aw = 0.f;
        #pragma unroll
        for (int j = 0; j < 16; ++j) {
            float4 v = wr[j];
            ax += v.x * v.x; ay += v.y * v.y; az += v.z * v.z; aw += v.w * v.w;
        }
        out[O_NW + i] = (ax + ay) + (az + aw);
    }
    if (i == 0) *loss_acc = 0.0;
}

__device__ inline void split8(float4 a, float4 b, f16x8& hi, f16x8& lo) {
    float vv[8] = {a.x, a.y, a.z, a.w, b.x, b.y, b.z, b.w};
    #pragma unroll
    for (int j = 0; j < 8; ++j) {
        float X = vv[j] * 256.0f;           // x*2^8
        _Float16 h = (_Float16)X;
        float r = X - (float)h;             // exact (Sterbenz)
        hi[j] = h;
        lo[j] = (_Float16)(r * 4096.0f);    // residual*2^12
    }
}

// ---------------- Kernel B: MFMA fused score + argmin (split-K) ----------------
// grid (512, NSPLIT) x 256 thr (4 waves). Wave w owns 32 rows (2 row-subtiles
// of 16); scans KSPL codes in 128 steps of 16. Per step: 4 B-fragment loads
// (L2) feed 12 MFMAs (B reused across both row-subtiles). Depth-2 prefetch
// via 2-slot register buffers, manually unrolled x2.
__global__ __launch_bounds__(256, 3)
void vq_argmin_mfma(const float* __restrict__ x,
                    const _Float16* __restrict__ ehi,
                    const _Float16* __restrict__ elo,
                    const float* __restrict__ Ag,
                    const float* __restrict__ b2g,
                    float* __restrict__ spart,
                    float* __restrict__ ipart) {
    __shared__ __align__(16) float b2sh[KSPL];
    const int tid = threadIdx.x;
    const int k0  = blockIdx.y * KSPL;
    #pragma unroll
    for (int j = 0; j < KSPL / 1024; ++j)
        ((float4*)b2sh)[tid + j * 256] = ((const float4*)(b2g + k0))[tid + j * 256];
    __syncthreads();

    const int l   = tid & 63;
    const int w   = tid >> 6;
    const int g   = l >> 4;        // k-group (0..3)
    const int c16 = l & 15;        // A: row within tile / B: code within tile
    const int rowbase = blockIdx.x * 128 + w * 32;

    // A-operand fragments for 2 row-subtiles: rows rowbase + r*16 + c16
    f16x8 xh[2][2], xl[2][2];
    #pragma unroll
    for (int r = 0; r < 2; ++r) {
        const float* xr = x + (size_t)(rowbase + r * 16 + c16) * DDIM + g * 8;
        float4 a0 = *(const float4*)(xr);
        float4 a1 = *(const float4*)(xr + 4);
        float4 a2 = *(const float4*)(xr + 32);
        float4 a3 = *(const float4*)(xr + 36);
        split8(a0, a1, xh[r][0], xl[r][0]);
        split8(a2, a3, xh[r][1], xl[r][1]);
    }
    // per-lane epilogue rows: r*16 + 4*g + v  (C/D: col=lane&15, row=(lane>>4)*4+v)
    float A_reg[2][4];
    #pragma unroll
    for (int r = 0; r < 2; ++r)
        #pragma unroll
        for (int v = 0; v < 4; ++v)
            A_reg[r][v] = Ag[rowbase + r * 16 + 4 * g + v];

    float bestv[2][4]; int bidx[2][4];
    #pragma unroll
    for (int r = 0; r < 2; ++r)
        #pragma unroll
        for (int v = 0; v < 4; ++v) { bestv[r][v] = INFINITY; bidx[r][v] = 0; }

    const _Float16* pbh = ehi + (size_t)(k0 + c16) * DDIM + g * 8;
    const _Float16* pbl = elo + (size_t)(k0 + c16) * DDIM + g * 8;

    f16x8 bh0[2], bh1[2], bl0[2], bl1[2];
    float b2r[2];

#define LOADB(sl, st) do {                                   \
        const size_t _o = (size_t)(st) * 1024;               \
        bh0[sl] = *(const f16x8*)(pbh + _o);                 \
        bh1[sl] = *(const f16x8*)(pbh + _o + 32);            \
        bl0[sl] = *(const f16x8*)(pbl + _o);                 \
        bl1[sl] = *(const f16x8*)(pbl + _o + 32);            \
        b2r[sl] = b2sh[(st) * 16 + c16];                     \
    } while (0)

#define COMP(sl, st) do {                                                         \
        f32x4 acc1[2], acc2[2];                                                   \
        _Pragma("unroll")                                                         \
        for (int r = 0; r < 2; ++r) {                                             \
            acc1[r] = (f32x4){0.f, 0.f, 0.f, 0.f};                                \
            acc2[r] = (f32x4){0.f, 0.f, 0.f, 0.f};                                \
            acc1[r] = __builtin_amdgcn_mfma_f32_16x16x32_f16(xh[r][0], bh0[sl], acc1[r], 0, 0, 0); \
            acc1[r] = __builtin_amdgcn_mfma_f32_16x16x32_f16(xh[r][1], bh1[sl], acc1[r], 0, 0, 0); \
            acc2[r] = __builtin_amdgcn_mfma_f32_16x16x32_f16(xl[r][0], bh0[sl], acc2[r], 0, 0, 0); \
            acc2[r] = __builtin_amdgcn_mfma_f32_16x16x32_f16(xl[r][1], bh1[sl], acc2[r], 0, 0, 0); \
            acc2[r] = __builtin_amdgcn_mfma_f32_16x16x32_f16(xh[r][0], bl0[sl], acc2[r], 0, 0, 0); \
            acc2[r] = __builtin_amdgcn_mfma_f32_16x16x32_f16(xh[r][1], bl1[sl], acc2[r], 0, 0, 0); \
        }                                                                         \
        const int _c = k0 + (st) * 16 + c16;                                      \
        _Pragma("unroll")                                                         \
        for (int r = 0; r < 2; ++r) {                                             \
            _Pragma("unroll")                                                     \
            for (int v = 0; v < 4; ++v) {                                         \
                float dotc = fmaf(acc2[r][v], 0x1p-12f, acc1[r][v]);              \
                float t = A_reg[r][v] + b2r[sl];                                  \
                float sc = fmaf(dotc, -0x1p-19f, t);                              \
                if (sc < bestv[r][v]) { bestv[r][v] = sc; bidx[r][v] = _c; }      \
            }                                                                     \
        }                                                                         \
    } while (0)

    LOADB(0, 0);
    LOADB(1, 1);

    #pragma unroll 1
    for (int s = 0; s < STEPS; s += 2) {
        COMP(0, s);
        LOADB(0, (s + 2) & (STEPS - 1));    // wrap: dead loads on last iter
        COMP(1, s + 1);
        LOADB(1, (s + 3) & (STEPS - 1));
    }
#undef LOADB
#undef COMP

    // reduce (value, then lowest index) across the 16 lanes of each k-group
    #pragma unroll
    for (int off = 1; off < 16; off <<= 1) {
        #pragma unroll
        for (int r = 0; r < 2; ++r)
            #pragma unroll
            for (int v = 0; v < 4; ++v) {
                float ob = __shfl_xor(bestv[r][v], off);
                int   oi = __shfl_xor(bidx[r][v], off);
                if (ob < bestv[r][v] || (ob == bestv[r][v] && oi < bidx[r][v])) {
                    bestv[r][v] = ob; bidx[r][v] = oi;
                }
            }
    }
    if (c16 == 0) {
        #pragma unroll
        for (int r = 0; r < 2; ++r)
            #pragma unroll
            for (int v = 0; v < 4; ++v) {
                const int row = rowbase + r * 16 + 4 * g + v;
                spart[(size_t)row * NSPLIT + blockIdx.y] = bestv[r][v];
                ipart[(size_t)row * NSPLIT + blockIdx.y] = (float)bidx[r][v];
            }
    }
}

// ---------------- Kernel B2: merge split partials -> indices ----------------
__global__ __launch_bounds__(256)
void vq_merge(const float* __restrict__ spart, const float* __restrict__ ipart,
              float* __restrict__ oidx) {
    int n = blockIdx.x * 256 + threadIdx.x;
    float best = INFINITY, bi = 0.f;
    #pragma unroll
    for (int s = 0; s < NSPLIT; ++s) {          // ascending splits = ascending idx
        float v = spart[(size_t)n * NSPLIT + s];
        float id = ipart[(size_t)n * NSPLIT + s];
        if (v < best) { best = v; bi = id; }    // strict <: lowest idx on tie
    }
    oidx[n] = bi;
}

// ---------------- Kernel C: gather + ST output + dw/count atomics + loss ----------------
__global__ __launch_bounds__(256)
void vq_gather(const float* __restrict__ x, const float* __restrict__ w,
               float* __restrict__ out, double* __restrict__ loss_acc) {
    const int tid = threadIdx.x;
    const int l16 = tid & 15;
    const int row = blockIdx.x * 16 + (tid >> 4);
    const int k = (int)out[O_IDX + row];
    const float4 w4 = ((const float4*)(w + (size_t)k * DDIM))[l16];
    const float4 x4 = ((const float4*)(x + (size_t)row * DDIM))[l16];
    float4 o;
    o.x = x4.x + (w4.x - x4.x);
    o.y = x4.y + (w4.y - x4.y);
    o.z = x4.z + (w4.z - x4.z);
    o.w = x4.w + (w4.w - x4.w);
    ((float4*)(out + O_Q + (size_t)row * DDIM))[l16] = o;
    float* dwp = out + O_NEW + (size_t)k * DDIM + l16 * 4;
    atomicAdd(dwp + 0, 0.01f * x4.x);
    atomicAdd(dwp + 1, 0.01f * x4.y);
    atomicAdd(dwp + 2, 0.01f * x4.z);
    atomicAdd(dwp + 3, 0.01f * x4.w);
    if (l16 == 0) atomicAdd(out + O_CS + k, 1.0f);
    float dx = w4.x - x4.x, dy = w4.y - x4.y, dz = w4.z - x4.z, dw_ = w4.w - x4.w;
    float e = dx * dx + dy * dy + dz * dz + dw_ * dw_;
    #pragma unroll
    for (int off = 32; off > 0; off >>= 1) e += __shfl_down(e, off);
    if ((tid & 63) == 0) atomicAdd(loss_acc, (double)e);
}

// ---------------- Kernel D: Laplace smoothing + loss write ----------------
__global__ __launch_bounds__(1024)
void vq_cs(const float* __restrict__ ecs, float* __restrict__ out,
           const double* __restrict__ loss_acc) {
    __shared__ float red[1024];
    const int tid = threadIdx.x;
    float cs[4];
    float local = 0.f;
    #pragma unroll
    for (int j = 0; j < 4; ++j) {
        int k = j * 1024 + tid;
        float cnt = out[O_CS + k];
        cs[j] = ecs[k] * 0.99f + 0.01f * cnt;
        local += cs[j];
    }
    red[tid] = local;
    for (int s = 512; s > 0; s >>= 1) {
        __syncthreads();
        if (tid < s) red[tid] += red[tid + s];
    }
    __syncthreads();
    const float n = red[0];
    const float denom = n + 0.04096f;
    #pragma unroll
    for (int j = 0; j < 4; ++j) {
        int k = j * 1024 + tid;
        out[O_CS + k] = (cs[j] + 1e-5f) / denom * n;
    }
    if (tid == 0) out[O_LOSS] = 1.25f * (float)(*loss_acc / 4194304.0);
}

// ---------------- Kernel E: new_weight = new_ema_w / cs ----------------
__global__ __launch_bounds__(256)
void vq_final(float* __restrict__ out) {
    int i = blockIdx.x * 256 + threadIdx.x;
    if (i >= KCODE * DDIM) return;
    int k = i >> 6;
    out[O_NW + i] = out[O_NEW + i] / out[O_CS + k];
}

extern "C" void kernel_launch(void* const* d_in, const int* in_sizes, int n_in,
                              void* d_out, int out_size, void* d_ws, size_t ws_size,
                              hipStream_t stream) {
    (void)in_sizes; (void)n_in; (void)out_size; (void)ws_size;
    const float* x    = (const float*)d_in[0];
    const float* w    = (const float*)d_in[1];
    const float* ecs  = (const float*)d_in[2];
    const float* emaw = (const float*)d_in[3];
    float* out = (float*)d_out;
    double* lacc = (double*)d_ws;

    const _Float16* ehi = (const _Float16*)out;            // halves [0, 262144)
    const _Float16* elo = ((const _Float16*)out) + 262144; // halves [262144, 524288)
    const float*    Ag  = out + O_A;
    float* spart = out + O_SP;
    float* ipart = out + O_IP;

    vq_prep       <<<1024, 256, 0, stream>>>(x, w, emaw, out, lacc);
    vq_argmin_mfma<<<dim3(512, NSPLIT), 256, 0, stream>>>(x, ehi, elo, Ag,
                                                          out + O_NW, spart, ipart);
    vq_merge      <<<256, 256, 0, stream>>>(spart, ipart, out + O_IDX);
    vq_gather     <<<4096, 256, 0, stream>>>(x, w, out, lacc);
    vq_cs         <<<1, 1024, 0, stream>>>(ecs, out, lacc);
    vq_final      <<<1024, 256, 0, stream>>>(out);
}

// Round 4
// 469.647 us; speedup vs baseline: 1.6457x; 1.0090x over previous
//
#include <hip/hip_runtime.h>
#include <math.h>

#define NROWS 65536
#define DDIM  64
#define KCODE 4096
#define NSPLIT 2
#define KSPL  (KCODE / NSPLIT)
#define STEPS (KSPL / 16)          // 128
#define SMASK (STEPS - 1)

// output layout (float offsets), concatenated in reference return order
#define O_Q    0           // quantized_st [B,T,D] = 4194304
#define O_LOSS 4194304     // loss scalar
#define O_IDX  4194305     // encoding_indices [B,T] = 65536 (floats)
#define O_NW   4259841     // new_weight [K,D] = 262144
#define O_CS   4521985     // cs [K] = 4096
#define O_NEW  4526081     // new_ema_w [K,D] = 262144

// scratch inside O_Q (dead once vq_gather starts writing Q rows):
//   E_hi : halves [0, 262144)        = floats [0, 131072)
//   E_lo : halves [262144, 524288)   = floats [131072, 262144)
//   A    : floats [262144, 327680)
//   B2   : floats [327680, 331776)
// scratch inside O_NW (read by vq_gather, clobbered only by vq_final):
//   spart: O_NW + [0, 131072)
//   ipart: O_NW + [131072, 262144)
#define O_A    262144
#define O_B2   327680

typedef _Float16 f16x8 __attribute__((ext_vector_type(8)));
typedef float    f32x4 __attribute__((ext_vector_type(4)));

// ---------------- Kernel A: init + splits + norms (load-balanced) ----------------
__global__ __launch_bounds__(256)
void vq_prep(const float* __restrict__ x, const float* __restrict__ w,
             const float* __restrict__ ema_w, float* __restrict__ out,
             double* __restrict__ loss_acc) {
    int i = blockIdx.x * 256 + threadIdx.x;   // grid = 262144 threads exactly
    // table split + EMA init (coalesced, all threads)
    {
        out[O_NEW + i] = 0.99f * ema_w[i];
        float E = w[i] * 4096.0f;             // scaled f16 split of codes
        _Float16 h = (_Float16)E;
        float r = E - (float)h;
        _Float16 lo = (_Float16)(r * 4096.0f);
        ((_Float16*)out)[i] = h;
        ((_Float16*)out)[262144 + i] = lo;
    }
    // x-norms: thread 4r handles row r (spread across ALL blocks; EXACT same
    // per-row summation order as validated rounds)
    if ((i & 3) == 0) {
        const int row = i >> 2;               // 0..65535
        const float4* xr = (const float4*)(x + (size_t)row * DDIM);
        float ax = 0.f, ay = 0.f, az = 0.f, aw = 0.f;
        #pragma unroll
        for (int j = 0; j < 16; ++j) {
            float4 v = xr[j];
            ax += v.x * v.x; ay += v.y * v.y; az += v.z * v.z; aw += v.w * v.w;
        }
        out[O_A + row] = (ax + ay) + (az + aw);
    }
    // w-norms: thread 64k handles code k; also zero the count slot
    if ((i & 63) == 0) {
        const int k = i >> 6;                 // 0..4095
        out[O_CS + k] = 0.0f;
        const float4* wr = (const float4*)(w + (size_t)k * DDIM);
        float ax = 0.f, ay = 0.f, az = 0.f, aw = 0.f;
        #pragma unroll
        for (int j = 0; j < 16; ++j) {
            float4 v = wr[j];
            ax += v.x * v.x; ay += v.y * v.y; az += v.z * v.z; aw += v.w * v.w;
        }
        out[O_B2 + k] = (ax + ay) + (az + aw);
    }
    if (i == 0) *loss_acc = 0.0;
}

__device__ inline void split8(float4 a, float4 b, f16x8& hi, f16x8& lo) {
    float vv[8] = {a.x, a.y, a.z, a.w, b.x, b.y, b.z, b.w};
    #pragma unroll
    for (int j = 0; j < 8; ++j) {
        float X = vv[j] * 256.0f;           // x*2^8
        _Float16 h = (_Float16)X;
        float r = X - (float)h;             // exact (Sterbenz)
        hi[j] = h;
        lo[j] = (_Float16)(r * 4096.0f);    // residual*2^12
    }
}

// ---------------- Kernel B: MFMA fused score + argmin (split-K, staggered) ----------------
// grid (512, NSPLIT) x 256 thr (4 waves). Wave w owns 32 rows; scans KSPL codes
// in 128 steps of 16 starting at a per-block staggered offset (breaks the
// all-waves-read-same-L2-line hotspot). Explicit (value, lowest-index)
// tie-break keeps argmin scan-order independent.
__global__ __launch_bounds__(256, 3)
void vq_argmin_mfma(const float* __restrict__ x,
                    const _Float16* __restrict__ ehi,
                    const _Float16* __restrict__ elo,
                    const float* __restrict__ Ag,
                    const float* __restrict__ b2g,
                    float* __restrict__ spart,
                    float* __restrict__ ipart) {
    __shared__ __align__(16) float b2sh[KSPL];
    const int tid = threadIdx.x;
    const int k0  = blockIdx.y * KSPL;
    #pragma unroll
    for (int j = 0; j < KSPL / 1024; ++j)
        ((float4*)b2sh)[tid + j * 256] = ((const float4*)(b2g + k0))[tid + j * 256];
    __syncthreads();

    const int l   = tid & 63;
    const int w   = tid >> 6;
    const int g   = l >> 4;        // k-group (0..3)
    const int c16 = l & 15;        // A: row within tile / B: code within tile
    const int rowbase = blockIdx.x * 128 + w * 32;
    const int soff = blockIdx.x & SMASK;   // stagger: de-correlate L2 line reads

    // A-operand fragments for 2 row-subtiles: rows rowbase + r*16 + c16
    f16x8 xh[2][2], xl[2][2];
    #pragma unroll
    for (int r = 0; r < 2; ++r) {
        const float* xr = x + (size_t)(rowbase + r * 16 + c16) * DDIM + g * 8;
        float4 a0 = *(const float4*)(xr);
        float4 a1 = *(const float4*)(xr + 4);
        float4 a2 = *(const float4*)(xr + 32);
        float4 a3 = *(const float4*)(xr + 36);
        split8(a0, a1, xh[r][0], xl[r][0]);
        split8(a2, a3, xh[r][1], xl[r][1]);
    }
    // per-lane epilogue rows: r*16 + 4*g + v  (C/D: col=lane&15, row=(lane>>4)*4+v)
    float A_reg[2][4];
    #pragma unroll
    for (int r = 0; r < 2; ++r)
        #pragma unroll
        for (int v = 0; v < 4; ++v)
            A_reg[r][v] = Ag[rowbase + r * 16 + 4 * g + v];

    float bestv[2][4]; int bidx[2][4];
    #pragma unroll
    for (int r = 0; r < 2; ++r)
        #pragma unroll
        for (int v = 0; v < 4; ++v) { bestv[r][v] = INFINITY; bidx[r][v] = 0x7FFFFFFF; }

    const _Float16* pbh = ehi + (size_t)(k0 + c16) * DDIM + g * 8;
    const _Float16* pbl = elo + (size_t)(k0 + c16) * DDIM + g * 8;

    f16x8 bh0[2], bh1[2], bl0[2], bl1[2];
    float b2r[2];

#define LOADB(sl, stv) do {                                  \
        const size_t _o = (size_t)(stv) * 1024;              \
        bh0[sl] = *(const f16x8*)(pbh + _o);                 \
        bh1[sl] = *(const f16x8*)(pbh + _o + 32);            \
        bl0[sl] = *(const f16x8*)(pbl + _o);                 \
        bl1[sl] = *(const f16x8*)(pbl + _o + 32);            \
        b2r[sl] = b2sh[(stv) * 16 + c16];                    \
    } while (0)

#define COMP(sl, stv) do {                                                        \
        f32x4 acc1[2], acc2[2];                                                   \
        _Pragma("unroll")                                                         \
        for (int r = 0; r < 2; ++r) {                                             \
            acc1[r] = (f32x4){0.f, 0.f, 0.f, 0.f};                                \
            acc2[r] = (f32x4){0.f, 0.f, 0.f, 0.f};                                \
            acc1[r] = __builtin_amdgcn_mfma_f32_16x16x32_f16(xh[r][0], bh0[sl], acc1[r], 0, 0, 0); \
            acc1[r] = __builtin_amdgcn_mfma_f32_16x16x32_f16(xh[r][1], bh1[sl], acc1[r], 0, 0, 0); \
            acc2[r] = __builtin_amdgcn_mfma_f32_16x16x32_f16(xl[r][0], bh0[sl], acc2[r], 0, 0, 0); \
            acc2[r] = __builtin_amdgcn_mfma_f32_16x16x32_f16(xl[r][1], bh1[sl], acc2[r], 0, 0, 0); \
            acc2[r] = __builtin_amdgcn_mfma_f32_16x16x32_f16(xh[r][0], bl0[sl], acc2[r], 0, 0, 0); \
            acc2[r] = __builtin_amdgcn_mfma_f32_16x16x32_f16(xh[r][1], bl1[sl], acc2[r], 0, 0, 0); \
        }                                                                         \
        const int _c = k0 + (stv) * 16 + c16;                                     \
        _Pragma("unroll")                                                         \
        for (int r = 0; r < 2; ++r) {                                             \
            _Pragma("unroll")                                                     \
            for (int v = 0; v < 4; ++v) {                                         \
                float dotc = fmaf(acc2[r][v], 0x1p-12f, acc1[r][v]);              \
                float t = A_reg[r][v] + b2r[sl];                                  \
                float sc = fmaf(dotc, -0x1p-19f, t);                              \
                if (sc < bestv[r][v] ||                                           \
                    (sc == bestv[r][v] && _c < bidx[r][v])) {                     \
                    bestv[r][v] = sc; bidx[r][v] = _c;                            \
                }                                                                 \
            }                                                                     \
        }                                                                         \
    } while (0)

    { const int st = soff & SMASK;       LOADB(0, st); }
    { const int st = (soff + 1) & SMASK; LOADB(1, st); }

    #pragma unroll 1
    for (int s = 0; s < STEPS; s += 2) {
        { const int st = (soff + s) & SMASK;     COMP(0, st); }
        { const int st = (soff + s + 2) & SMASK; LOADB(0, st); }   // wrap: dead loads at end
        { const int st = (soff + s + 1) & SMASK; COMP(1, st); }
        { const int st = (soff + s + 3) & SMASK; LOADB(1, st); }
    }
#undef LOADB
#undef COMP

    // reduce (value, then lowest index) across the 16 lanes of each k-group
    #pragma unroll
    for (int off = 1; off < 16; off <<= 1) {
        #pragma unroll
        for (int r = 0; r < 2; ++r)
            #pragma unroll
            for (int v = 0; v < 4; ++v) {
                float ob = __shfl_xor(bestv[r][v], off);
                int   oi = __shfl_xor(bidx[r][v], off);
                if (ob < bestv[r][v] || (ob == bestv[r][v] && oi < bidx[r][v])) {
                    bestv[r][v] = ob; bidx[r][v] = oi;
                }
            }
    }
    if (c16 == 0) {
        #pragma unroll
        for (int r = 0; r < 2; ++r)
            #pragma unroll
            for (int v = 0; v < 4; ++v) {
                const int row = rowbase + r * 16 + 4 * g + v;
                spart[(size_t)row * NSPLIT + blockIdx.y] = bestv[r][v];
                ipart[(size_t)row * NSPLIT + blockIdx.y] = (float)bidx[r][v];
            }
    }
}

// ---------------- Kernel C: merge + gather + ST output + dw/count atomics + loss ----------------
__global__ __launch_bounds__(256)
void vq_gather(const float* __restrict__ x, const float* __restrict__ w,
               const float* __restrict__ spart, const float* __restrict__ ipart,
               float* __restrict__ out, double* __restrict__ loss_acc) {
    const int tid = threadIdx.x;
    const int l16 = tid & 15;
    const int row = blockIdx.x * 16 + (tid >> 4);
    // merge split partials (redundant across the 16 lanes; same L2 lines)
    float best = INFINITY, bi = 0.f;
    #pragma unroll
    for (int s = 0; s < NSPLIT; ++s) {          // ascending splits = ascending idx ranges
        float v  = spart[(size_t)row * NSPLIT + s];
        float id = ipart[(size_t)row * NSPLIT + s];
        if (v < best) { best = v; bi = id; }    // strict <: lowest idx on tie
    }
    const int k = (int)bi;
    if (l16 == 0) out[O_IDX + row] = bi;

    const float4 w4 = ((const float4*)(w + (size_t)k * DDIM))[l16];
    const float4 x4 = ((const float4*)(x + (size_t)row * DDIM))[l16];
    float4 o;
    o.x = x4.x + (w4.x - x4.x);
    o.y = x4.y + (w4.y - x4.y);
    o.z = x4.z + (w4.z - x4.z);
    o.w = x4.w + (w4.w - x4.w);
    ((float4*)(out + O_Q + (size_t)row * DDIM))[l16] = o;
    float* dwp = out + O_NEW + (size_t)k * DDIM + l16 * 4;
    atomicAdd(dwp + 0, 0.01f * x4.x);
    atomicAdd(dwp + 1, 0.01f * x4.y);
    atomicAdd(dwp + 2, 0.01f * x4.z);
    atomicAdd(dwp + 3, 0.01f * x4.w);
    if (l16 == 0) atomicAdd(out + O_CS + k, 1.0f);
    float dx = w4.x - x4.x, dy = w4.y - x4.y, dz = w4.z - x4.z, dw_ = w4.w - x4.w;
    float e = dx * dx + dy * dy + dz * dz + dw_ * dw_;
    #pragma unroll
    for (int off = 32; off > 0; off >>= 1) e += __shfl_down(e, off);
    if ((tid & 63) == 0) atomicAdd(loss_acc, (double)e);
}

// ---------------- Kernel D: Laplace smoothing + loss write ----------------
__global__ __launch_bounds__(1024)
void vq_cs(const float* __restrict__ ecs, float* __restrict__ out,
           const double* __restrict__ loss_acc) {
    __shared__ float red[1024];
    const int tid = threadIdx.x;
    float cs[4];
    float local = 0.f;
    #pragma unroll
    for (int j = 0; j < 4; ++j) {
        int k = j * 1024 + tid;
        float cnt = out[O_CS + k];
        cs[j] = ecs[k] * 0.99f + 0.01f * cnt;
        local += cs[j];
    }
    red[tid] = local;
    for (int s = 512; s > 0; s >>= 1) {
        __syncthreads();
        if (tid < s) red[tid] += red[tid + s];
    }
    __syncthreads();
    const float n = red[0];
    const float denom = n + 0.04096f;
    #pragma unroll
    for (int j = 0; j < 4; ++j) {
        int k = j * 1024 + tid;
        out[O_CS + k] = (cs[j] + 1e-5f) / denom * n;
    }
    if (tid == 0) out[O_LOSS] = 1.25f * (float)(*loss_acc / 4194304.0);
}

// ---------------- Kernel E: new_weight = new_ema_w / cs ----------------
__global__ __launch_bounds__(256)
void vq_final(float* __restrict__ out) {
    int i = blockIdx.x * 256 + threadIdx.x;
    if (i >= KCODE * DDIM) return;
    int k = i >> 6;
    out[O_NW + i] = out[O_NEW + i] / out[O_CS + k];
}

extern "C" void kernel_launch(void* const* d_in, const int* in_sizes, int n_in,
                              void* d_out, int out_size, void* d_ws, size_t ws_size,
                              hipStream_t stream) {
    (void)in_sizes; (void)n_in; (void)out_size; (void)ws_size;
    const float* x    = (const float*)d_in[0];
    const float* w    = (const float*)d_in[1];
    const float* ecs  = (const float*)d_in[2];
    const float* emaw = (const float*)d_in[3];
    float* out = (float*)d_out;
    double* lacc = (double*)d_ws;

    const _Float16* ehi = (const _Float16*)out;            // halves [0, 262144)
    const _Float16* elo = ((const _Float16*)out) + 262144; // halves [262144, 524288)
    const float*    Ag  = out + O_A;
    float* spart = out + O_NW;                 // lives until vq_final
    float* ipart = out + O_NW + 131072;

    vq_prep       <<<1024, 256, 0, stream>>>(x, w, emaw, out, lacc);
    vq_argmin_mfma<<<dim3(512, NSPLIT), 256, 0, stream>>>(x, ehi, elo, Ag,
                                                          out + O_B2, spart, ipart);
    vq_gather     <<<4096, 256, 0, stream>>>(x, w, spart, ipart, out, lacc);
    vq_cs         <<<1, 1024, 0, stream>>>(ecs, out, lacc);
    vq_final      <<<1024, 256, 0, stream>>>(out);
}